// Round 1
// baseline (192.461 us; speedup 1.0000x reference)
//
#include <hip/hip_runtime.h>
#include <hip/hip_bf16.h>

// Problem: HybridBCEDiceBoundaryLoss — scalar loss over logits/targets (32,1,512,512) fp32.
// loss = 0.3*BCE + 0.3*Dice + 0.2*BoundaryBCE + 0.2*LovaszHinge(per image mean)
//
// Lovasz computed WITHOUT sorting via histogram + suffix-scan:
//   L = sum_i relu(e_i) * dJ_i,  dJ = 1/u (pos) or (P-c)/(u*(u-1)) (neg),
//   where u,c depend only on counts of elements with larger error. Elements with
//   e<=0 contribute 0 and never affect ranks of contributing elements.

#define NB      32
#define HH      512
#define WW      512
#define HW      (HH*WW)          // 262144
#define NTOT    (NB*HW)          // 8388608
#define K_BINS  2048
#define INV_H   256.0f           // K_BINS / range(8.0)
#define CHUNKS  32               // blocks per image; 8192 elems/block

struct Ws {
    unsigned cnt_all[NB*K_BINS];
    unsigned cnt_pos[NB*K_BINS];
    float    sum_all[NB*K_BINS];
    float    sum_pos[NB*K_BINS];
    float    sy[NB];
    float    spy[NB];
    float    Pim[NB];
    float    bce_sum;
    float    bceE_sum;
    float    lov_sum;
};

__global__ __launch_bounds__(256) void kernelA(const float* __restrict__ logits,
                                               const float* __restrict__ targets,
                                               Ws* __restrict__ ws) {
    __shared__ unsigned s_cnt_all[K_BINS];
    __shared__ unsigned s_cnt_pos[K_BINS];
    __shared__ float    s_sum_all[K_BINS];
    __shared__ float    s_sum_pos[K_BINS];
    __shared__ float    red[4][5];

    const int tid = threadIdx.x;
    for (int i = tid; i < K_BINS; i += 256) {
        s_cnt_all[i] = 0u; s_cnt_pos[i] = 0u;
        s_sum_all[i] = 0.f; s_sum_pos[i] = 0.f;
    }
    __syncthreads();

    const int img   = blockIdx.x / CHUNKS;
    const int chunk = blockIdx.x % CHUNKS;
    const float* __restrict__ lg = logits + img * HW;
    const float* __restrict__ tg = targets + img * HW;

    float bce_s = 0.f, bceE_s = 0.f, sy_s = 0.f, spy_s = 0.f, P_s = 0.f;
    const int base = chunk * 8192;

    for (int it = 0; it < 32; ++it) {
        const int idx = base + it * 256 + tid;
        const int r = idx >> 9;
        const int c = idx & 511;
        const float x = lg[idx];
        const float y = tg[idx];

        // stable BCE with logits (pos_weight=1)
        const float ax = fabsf(x);
        const float t  = __expf(-ax);               // exp(-|x|) in (0,1]
        const float bce = fmaxf(x, 0.f) - x * y + log1pf(t);

        // sigmoid from same exp
        const float s = (x >= 0.f) ? (1.f / (1.f + t)) : (t / (1.f + t));

        // 3x3 box count of targets (zero-padded SAME); edge iff 1..8 ones
        float wsum = y;
        {
            const float* rowp = tg + r * WW;
            if (c > 0)   wsum += rowp[c - 1];
            if (c < 511) wsum += rowp[c + 1];
        }
        if (r > 0) {
            const float* rowp = tg + (r - 1) * WW;
            wsum += rowp[c];
            if (c > 0)   wsum += rowp[c - 1];
            if (c < 511) wsum += rowp[c + 1];
        }
        if (r < 511) {
            const float* rowp = tg + (r + 1) * WW;
            wsum += rowp[c];
            if (c > 0)   wsum += rowp[c - 1];
            if (c < 511) wsum += rowp[c + 1];
        }
        const bool edge = (wsum > 0.5f) && (wsum < 8.5f);

        bce_s  += bce;
        bceE_s += edge ? bce : 0.f;
        sy_s   += s * y;
        spy_s  += s + y;
        P_s    += y;

        // lovasz error histogram (only e > 0 matters)
        const float sign = 2.f * y - 1.f;
        const float e = 1.f - x * sign;
        if (e > 0.f) {
            int b = (int)(e * INV_H);
            if (b > K_BINS - 1) b = K_BINS - 1;
            atomicAdd(&s_cnt_all[b], 1u);
            atomicAdd(&s_sum_all[b], e);
            if (y > 0.5f) {
                atomicAdd(&s_cnt_pos[b], 1u);
                atomicAdd(&s_sum_pos[b], e);
            }
        }
    }
    __syncthreads();

    // flush histograms
    unsigned* g_ca = ws->cnt_all + img * K_BINS;
    unsigned* g_cp = ws->cnt_pos + img * K_BINS;
    float*    g_sa = ws->sum_all + img * K_BINS;
    float*    g_sp = ws->sum_pos + img * K_BINS;
    for (int i = tid; i < K_BINS; i += 256) {
        if (s_cnt_all[i]) {
            atomicAdd(&g_ca[i], s_cnt_all[i]);
            atomicAdd(&g_sa[i], s_sum_all[i]);
            if (s_cnt_pos[i]) {
                atomicAdd(&g_cp[i], s_cnt_pos[i]);
                atomicAdd(&g_sp[i], s_sum_pos[i]);
            }
        }
    }

    // block reduction of 5 accumulators
    for (int off = 32; off; off >>= 1) {
        bce_s  += __shfl_down(bce_s, off);
        bceE_s += __shfl_down(bceE_s, off);
        sy_s   += __shfl_down(sy_s, off);
        spy_s  += __shfl_down(spy_s, off);
        P_s    += __shfl_down(P_s, off);
    }
    const int wave = tid >> 6;
    const int lane = tid & 63;
    if (lane == 0) {
        red[wave][0] = bce_s; red[wave][1] = bceE_s; red[wave][2] = sy_s;
        red[wave][3] = spy_s; red[wave][4] = P_s;
    }
    __syncthreads();
    if (tid == 0) {
        float a = 0.f, b = 0.f, c2 = 0.f, d = 0.f, e2 = 0.f;
        for (int w = 0; w < 4; ++w) {
            a += red[w][0]; b += red[w][1]; c2 += red[w][2];
            d += red[w][3]; e2 += red[w][4];
        }
        atomicAdd(&ws->bce_sum, a);
        atomicAdd(&ws->bceE_sum, b);
        atomicAdd(&ws->sy[img], c2);
        atomicAdd(&ws->spy[img], d);
        atomicAdd(&ws->Pim[img], e2);
    }
}

__global__ __launch_bounds__(256) void kernelB(Ws* __restrict__ ws) {
    __shared__ unsigned sc_a[256];
    __shared__ unsigned sc_p[256];
    __shared__ double   dred[4];

    const int img = blockIdx.x;
    const int tid = threadIdx.x;
    const unsigned* __restrict__ ca = ws->cnt_all + img * K_BINS;
    const unsigned* __restrict__ cp = ws->cnt_pos + img * K_BINS;
    const float*    __restrict__ sa = ws->sum_all + img * K_BINS;
    const float*    __restrict__ sp = ws->sum_pos + img * K_BINS;

    // each thread handles 8 bins in descending-bin order
    unsigned la[8], lp[8];
    float    fa[8], fp8[8];
    unsigned tot_a = 0, tot_p = 0;
    for (int j = 0; j < 8; ++j) {
        const int k = K_BINS - 1 - (tid * 8 + j);
        la[j] = ca[k]; lp[j] = cp[k]; fa[j] = sa[k]; fp8[j] = sp[k];
        tot_a += la[j]; tot_p += lp[j];
    }

    // block-wide inclusive scan of chunk totals (Hillis-Steele)
    sc_a[tid] = tot_a; sc_p[tid] = tot_p;
    __syncthreads();
    for (int off = 1; off < 256; off <<= 1) {
        unsigned va = (tid >= off) ? sc_a[tid - off] : 0u;
        unsigned vp = (tid >= off) ? sc_p[tid - off] : 0u;
        __syncthreads();
        sc_a[tid] += va; sc_p[tid] += vp;
        __syncthreads();
    }
    const unsigned excl_a = sc_a[tid] - tot_a;
    const unsigned excl_p = sc_p[tid] - tot_p;

    const double P = (double)ws->Pim[img];
    double run_a = (double)excl_a, run_p = (double)excl_p;
    double contrib = 0.0;
    for (int j = 0; j < 8; ++j) {
        const double m = (double)la[j];
        const double p = (double)lp[j];
        if (la[j]) {
            const double u = P + (run_a + 0.5 * m) - (run_p + 0.5 * p);
            const double c = run_p + 0.5 * p;
            contrib += (double)fp8[j] / u;                      // positives: dJ = 1/u
            const double den = u * (u - 1.0);
            if (den > 0.0)
                contrib += (double)(fa[j] - fp8[j]) * (P - c) / den;  // negatives
        }
        run_a += m; run_p += p;
    }

    // block reduce (double)
    for (int off = 32; off; off >>= 1) contrib += __shfl_down(contrib, off);
    const int wave = tid >> 6;
    const int lane = tid & 63;
    if (lane == 0) dred[wave] = contrib;
    __syncthreads();
    if (tid == 0) {
        double tot = dred[0] + dred[1] + dred[2] + dred[3];
        atomicAdd(&ws->lov_sum, (float)tot);
    }
}

__global__ __launch_bounds__(64) void kernelC(const Ws* __restrict__ ws,
                                              float* __restrict__ out) {
    const int lane = threadIdx.x;
    float dsum = 0.f;
    if (lane < NB) {
        const float num = 2.f * ws->sy[lane];
        const float den = ws->spy[lane] + 1e-7f;
        dsum = num / den;
    }
    for (int off = 32; off; off >>= 1) dsum += __shfl_down(dsum, off);
    if (lane == 0) {
        const float invN = 1.f / (float)NTOT;
        const float bce      = ws->bce_sum * invN;
        const float boundary = (ws->bce_sum + 2.f * ws->bceE_sum) * invN;
        const float dice     = 1.f - dsum / (float)NB;
        const float lov      = ws->lov_sum / (float)NB;
        out[0] = 0.3f * bce + 0.3f * dice + 0.2f * boundary + 0.2f * lov;
    }
}

extern "C" void kernel_launch(void* const* d_in, const int* in_sizes, int n_in,
                              void* d_out, int out_size, void* d_ws, size_t ws_size,
                              hipStream_t stream) {
    const float* logits  = (const float*)d_in[0];
    const float* targets = (const float*)d_in[1];
    float* out = (float*)d_out;
    Ws* ws = (Ws*)d_ws;

    hipMemsetAsync(d_ws, 0, sizeof(Ws), stream);
    kernelA<<<NB * CHUNKS, 256, 0, stream>>>(logits, targets, ws);
    kernelB<<<NB, 256, 0, stream>>>(ws);
    kernelC<<<1, 64, 0, stream>>>(ws, out);
}

// Round 2
// 172.657 us; speedup vs baseline: 1.1147x; 1.1147x over previous
//
#include <hip/hip_runtime.h>
#include <hip/hip_bf16.h>

// HybridBCEDiceBoundaryLoss — scalar loss over logits/targets (32,1,512,512) fp32.
// loss = 0.3*BCE + 0.3*Dice + 0.2*BoundaryBCE + 0.2*LovaszHinge(per-image mean)
//
// Lovasz without sorting: histogram over e in (0,8), 1024 bins, suffix-scan ranks,
// midpoint-in-bin (2nd-order accurate). Only e>0 elements matter (relu) and they
// are unaffected by e<=0 ranks.
//
// R1: float4 loads + shfl neighbor exchange for 3x3 stencil (was 9 scalar loads/px),
// 1024 bins / packed counts -> 12 KB LDS (was 33), CHUNKS 32->64 for occupancy.

#define NB      32
#define HH      512
#define WW      512
#define HW      (HH*WW)          // 262144
#define NTOT    (NB*HW)          // 8388608
#define K_BINS  1024
#define INV_H   128.0f           // K_BINS / 8.0 range
#define CHUNKS  64               // blocks per image; 4096 elems (1024 float4) per block
#define F4_PER_IMG (HW/4)        // 65536

struct Ws {
    unsigned cnt[NB*K_BINS];      // low16 = count_all, high16 = count_pos
    float    sum_pos[NB*K_BINS];
    float    sum_neg[NB*K_BINS];
    float    sy[NB];
    float    spy[NB];
    float    Pim[NB];
    float    bce_sum;
    float    bceE_sum;
    float    lov_sum;
};

__device__ __forceinline__ void process_elem(float x, float y, float wsum,
                                             float& bce_s, float& bceE_s, float& sy_s,
                                             float& spy_s, float& P_s,
                                             unsigned* s_cnt, float* s_sum_pos, float* s_sum_neg) {
    const float ax = fabsf(x);
    const float t  = __expf(-ax);                       // exp(-|x|)
    const float bce = fmaxf(x, 0.f) - x * y + __logf(1.f + t);
    const float inv = __builtin_amdgcn_rcpf(1.f + t);
    const float s = (x >= 0.f) ? inv : t * inv;         // sigmoid(x)
    const bool edge = (wsum > 0.5f) && (wsum < 8.5f);   // 1..8 of 9 ones

    bce_s  += bce;
    bceE_s += edge ? bce : 0.f;
    sy_s   += s * y;
    spy_s  += s + y;
    P_s    += y;

    const bool pos = (y > 0.5f);
    const float e = 1.f - x * (2.f * y - 1.f);
    if (e > 0.f) {
        int b = (int)(e * INV_H);
        if (b > K_BINS - 1) b = K_BINS - 1;
        atomicAdd(&s_cnt[b], pos ? 0x10001u : 1u);
        atomicAdd(pos ? &s_sum_pos[b] : &s_sum_neg[b], e);
    }
}

__global__ __launch_bounds__(256) void kernelA(const float* __restrict__ logits,
                                               const float* __restrict__ targets,
                                               Ws* __restrict__ ws) {
    __shared__ unsigned s_cnt[K_BINS];
    __shared__ float    s_sum_pos[K_BINS];
    __shared__ float    s_sum_neg[K_BINS];
    __shared__ float    red[4][5];

    const int tid  = threadIdx.x;
    const int lane = tid & 63;
    for (int i = tid; i < K_BINS; i += 256) {
        s_cnt[i] = 0u; s_sum_pos[i] = 0.f; s_sum_neg[i] = 0.f;
    }
    __syncthreads();

    const int img   = blockIdx.x / CHUNKS;
    const int chunk = blockIdx.x % CHUNKS;
    const float4* __restrict__ lg4 = (const float4*)(logits + img * HW);
    const float4* __restrict__ tg4 = (const float4*)(targets + img * HW);
    const float*  __restrict__ tg  = targets + img * HW;

    float bce_s = 0.f, bceE_s = 0.f, sy_s = 0.f, spy_s = 0.f, P_s = 0.f;

#pragma unroll
    for (int it = 0; it < 4; ++it) {
        const int f  = chunk * 1024 + it * 256 + tid;   // float4 index in image
        const int r  = f >> 7;                          // row
        const int c4 = f & 127;                         // col/4

        const float4 x4 = lg4[f];
        const float4 ym = tg4[f];
        float4 yt = make_float4(0.f, 0.f, 0.f, 0.f);
        float4 yb = make_float4(0.f, 0.f, 0.f, 0.f);
        if (r > 0)   yt = tg4[f - 128];
        if (r < 511) yb = tg4[f + 128];

        // column sums (rows r-1..r+1)
        const float cs0 = yt.x + ym.x + yb.x;
        const float cs1 = yt.y + ym.y + yb.y;
        const float cs2 = yt.z + ym.z + yb.z;
        const float cs3 = yt.w + ym.w + yb.w;

        // neighbor column sums via wave shuffle (lanes are consecutive f within a row half)
        const float upL = __shfl_up(cs3, 1);
        const float dnR = __shfl_down(cs0, 1);
        float csL, csR;
        if (lane == 0) {
            csL = 0.f;
            if (c4 != 0) {                              // c4 == 64 -> need col 255
                const int cc = c4 * 4 - 1;
                csL = tg[r * WW + cc];
                if (r > 0)   csL += tg[(r - 1) * WW + cc];
                if (r < 511) csL += tg[(r + 1) * WW + cc];
            }
        } else csL = upL;
        if (lane == 63) {
            csR = 0.f;
            if (c4 != 127) {                            // need col c+4
                const int cc = c4 * 4 + 4;
                csR = tg[r * WW + cc];
                if (r > 0)   csR += tg[(r - 1) * WW + cc];
                if (r < 511) csR += tg[(r + 1) * WW + cc];
            }
        } else csR = dnR;

        const float w0 = csL + cs0 + cs1;
        const float w1 = cs0 + cs1 + cs2;
        const float w2 = cs1 + cs2 + cs3;
        const float w3 = cs2 + cs3 + csR;

        process_elem(x4.x, ym.x, w0, bce_s, bceE_s, sy_s, spy_s, P_s, s_cnt, s_sum_pos, s_sum_neg);
        process_elem(x4.y, ym.y, w1, bce_s, bceE_s, sy_s, spy_s, P_s, s_cnt, s_sum_pos, s_sum_neg);
        process_elem(x4.z, ym.z, w2, bce_s, bceE_s, sy_s, spy_s, P_s, s_cnt, s_sum_pos, s_sum_neg);
        process_elem(x4.w, ym.w, w3, bce_s, bceE_s, sy_s, spy_s, P_s, s_cnt, s_sum_pos, s_sum_neg);
    }
    __syncthreads();

    // flush histogram to global
    unsigned* g_c  = ws->cnt     + img * K_BINS;
    float*    g_sp = ws->sum_pos + img * K_BINS;
    float*    g_sn = ws->sum_neg + img * K_BINS;
    for (int i = tid; i < K_BINS; i += 256) {
        const unsigned cpk = s_cnt[i];
        if (cpk) {
            atomicAdd(&g_c[i], cpk);
            const float sp = s_sum_pos[i];
            const float sn = s_sum_neg[i];
            if (sp != 0.f) atomicAdd(&g_sp[i], sp);
            if (sn != 0.f) atomicAdd(&g_sn[i], sn);
        }
    }

    // block reduction of 5 accumulators
    for (int off = 32; off; off >>= 1) {
        bce_s  += __shfl_down(bce_s, off);
        bceE_s += __shfl_down(bceE_s, off);
        sy_s   += __shfl_down(sy_s, off);
        spy_s  += __shfl_down(spy_s, off);
        P_s    += __shfl_down(P_s, off);
    }
    const int wave = tid >> 6;
    if (lane == 0) {
        red[wave][0] = bce_s; red[wave][1] = bceE_s; red[wave][2] = sy_s;
        red[wave][3] = spy_s; red[wave][4] = P_s;
    }
    __syncthreads();
    if (tid == 0) {
        float a = 0.f, b = 0.f, c2 = 0.f, d = 0.f, e2 = 0.f;
        for (int w = 0; w < 4; ++w) {
            a += red[w][0]; b += red[w][1]; c2 += red[w][2];
            d += red[w][3]; e2 += red[w][4];
        }
        atomicAdd(&ws->bce_sum, a);
        atomicAdd(&ws->bceE_sum, b);
        atomicAdd(&ws->sy[img], c2);
        atomicAdd(&ws->spy[img], d);
        atomicAdd(&ws->Pim[img], e2);
    }
}

__global__ __launch_bounds__(256) void kernelB(Ws* __restrict__ ws) {
    __shared__ unsigned sc_a[256];
    __shared__ unsigned sc_p[256];
    __shared__ double   dred[4];

    const int img = blockIdx.x;
    const int tid = threadIdx.x;
    const unsigned* __restrict__ cn = ws->cnt     + img * K_BINS;
    const float*    __restrict__ sp = ws->sum_pos + img * K_BINS;
    const float*    __restrict__ sn = ws->sum_neg + img * K_BINS;

    // each thread handles 4 bins in descending-bin order
    unsigned la[4], lp[4];
    float    fp_[4], fn_[4];
    unsigned tot_a = 0, tot_p = 0;
#pragma unroll
    for (int j = 0; j < 4; ++j) {
        const int k = K_BINS - 1 - (tid * 4 + j);
        const unsigned cpk = cn[k];
        la[j] = cpk & 0xFFFFu; lp[j] = cpk >> 16;
        fp_[j] = sp[k]; fn_[j] = sn[k];
        tot_a += la[j]; tot_p += lp[j];
    }

    // block-wide inclusive scan of per-thread totals
    sc_a[tid] = tot_a; sc_p[tid] = tot_p;
    __syncthreads();
    for (int off = 1; off < 256; off <<= 1) {
        unsigned va = (tid >= off) ? sc_a[tid - off] : 0u;
        unsigned vp = (tid >= off) ? sc_p[tid - off] : 0u;
        __syncthreads();
        sc_a[tid] += va; sc_p[tid] += vp;
        __syncthreads();
    }
    const unsigned excl_a = sc_a[tid] - tot_a;
    const unsigned excl_p = sc_p[tid] - tot_p;

    const double P = (double)ws->Pim[img];
    double run_a = (double)excl_a, run_p = (double)excl_p;
    double contrib = 0.0;
#pragma unroll
    for (int j = 0; j < 4; ++j) {
        const double m = (double)la[j];
        const double p = (double)lp[j];
        if (la[j]) {
            const double u = P + (run_a + 0.5 * m) - (run_p + 0.5 * p);
            const double c = run_p + 0.5 * p;
            contrib += (double)fp_[j] / u;                       // positives: dJ = 1/u
            const double den = u * (u - 1.0);
            if (den > 0.0)
                contrib += (double)fn_[j] * (P - c) / den;       // negatives
        }
        run_a += m; run_p += p;
    }

    for (int off = 32; off; off >>= 1) contrib += __shfl_down(contrib, off);
    const int wave = tid >> 6;
    const int lane = tid & 63;
    if (lane == 0) dred[wave] = contrib;
    __syncthreads();
    if (tid == 0) {
        double tot = dred[0] + dred[1] + dred[2] + dred[3];
        atomicAdd(&ws->lov_sum, (float)tot);
    }
}

__global__ __launch_bounds__(64) void kernelC(const Ws* __restrict__ ws,
                                              float* __restrict__ out) {
    const int lane = threadIdx.x;
    float dsum = 0.f;
    if (lane < NB) {
        const float num = 2.f * ws->sy[lane];
        const float den = ws->spy[lane] + 1e-7f;
        dsum = num / den;
    }
    for (int off = 32; off; off >>= 1) dsum += __shfl_down(dsum, off);
    if (lane == 0) {
        const float invN = 1.f / (float)NTOT;
        const float bce      = ws->bce_sum * invN;
        const float boundary = (ws->bce_sum + 2.f * ws->bceE_sum) * invN;
        const float dice     = 1.f - dsum / (float)NB;
        const float lov      = ws->lov_sum / (float)NB;
        out[0] = 0.3f * bce + 0.3f * dice + 0.2f * boundary + 0.2f * lov;
    }
}

extern "C" void kernel_launch(void* const* d_in, const int* in_sizes, int n_in,
                              void* d_out, int out_size, void* d_ws, size_t ws_size,
                              hipStream_t stream) {
    const float* logits  = (const float*)d_in[0];
    const float* targets = (const float*)d_in[1];
    float* out = (float*)d_out;
    Ws* ws = (Ws*)d_ws;

    hipMemsetAsync(d_ws, 0, sizeof(Ws), stream);
    kernelA<<<NB * CHUNKS, 256, 0, stream>>>(logits, targets, ws);
    kernelB<<<NB, 256, 0, stream>>>(ws);
    kernelC<<<1, 64, 0, stream>>>(ws, out);
}

// Round 4
// 130.756 us; speedup vs baseline: 1.4719x; 1.3204x over previous
//
#include <hip/hip_runtime.h>
#include <hip/hip_bf16.h>

// HybridBCEDiceBoundaryLoss — scalar loss over logits/targets (32,1,512,512) fp32.
// loss = 0.3*BCE + 0.3*Dice + 0.2*BoundaryBCE + 0.2*LovaszHinge(per-image mean)
//
// Lovasz without sorting: counts-only histogram over e in (0,8), 1024 bins,
// suffix-scan ranks, bin-midpoint values (2nd-order accurate).
//
// R3: 8-row vertical register tile (target rows loaded 1.25x instead of 3x),
// counts-only histogram (1 LDS atomic/elem, 1 global flush array),
// LDS boundary exchange (no edge scalar loads), 1024 blocks.

#define NB      32
#define HH      512
#define WW      512
#define HW      (HH*WW)          // 262144
#define NTOT    (NB*HW)          // 8388608
#define K_BINS  1024
#define INV_H   128.0f           // K_BINS / 8.0 range
#define BIN_W   (1.0f/128.0f)
#define BPI     32               // blocks per image; block = 16 rows x 512 cols

struct Ws {
    unsigned cnt[NB*K_BINS];      // low16 = count_all, high16 = count_pos
    float    sy[NB];
    float    spy[NB];
    float    Pim[NB];
    float    bce_sum;
    float    bceE_sum;
    float    lov_sum;
};

__device__ __forceinline__ void process_elem(float x, float y, float wsum,
                                             float& bce_s, float& bceE_s, float& sy_s,
                                             float& spy_s, float& P_s,
                                             unsigned* s_cnt) {
    const float ax = fabsf(x);
    const float t  = __expf(-ax);                       // exp(-|x|)
    const float bce = fmaxf(x, 0.f) - x * y + __logf(1.f + t);
    const float inv = __builtin_amdgcn_rcpf(1.f + t);
    const float s = (x >= 0.f) ? inv : t * inv;         // sigmoid(x)
    const bool edge = (wsum > 0.5f) && (wsum < 8.5f);   // 1..8 of 9 ones

    bce_s  += bce;
    bceE_s += edge ? bce : 0.f;
    sy_s   += s * y;
    spy_s  += s + y;
    P_s    += y;

    const float e = 1.f - x * (2.f * y - 1.f);
    if (e > 0.f) {
        int b = (int)(e * INV_H);
        if (b > K_BINS - 1) b = K_BINS - 1;
        atomicAdd(&s_cnt[b], (y > 0.5f) ? 0x10001u : 1u);
    }
}

__global__ __launch_bounds__(256) void kernelA(const float* __restrict__ logits,
                                               const float* __restrict__ targets,
                                               Ws* __restrict__ ws) {
    __shared__ unsigned s_cnt[K_BINS];
    __shared__ float    s_bL[2][8];   // col-255 triple-sums (written by half0 lane63)
    __shared__ float    s_bR[2][8];   // col-256 triple-sums (written by half1 lane0)
    __shared__ float    red[4][5];

    const int tid   = threadIdx.x;
    const int lane  = tid & 63;
    const int wave  = tid >> 6;
    const int half  = wave & 1;       // 0 = cols 0..255, 1 = cols 256..511
    const int strip = wave >> 1;      // 0 = rows r0..r0+7, 1 = rows r0+8..r0+15

    for (int i = tid; i < K_BINS; i += 256) s_cnt[i] = 0u;

    const int img = blockIdx.x >> 5;
    const int blk = blockIdx.x & 31;
    const int r0  = blk * 16 + strip * 8;       // first output row of this wave
    const int c4  = half * 64 + lane;           // float4 column index 0..127

    const float4* __restrict__ tg4 = (const float4*)(targets + img * HW);
    const float4* __restrict__ lg4 = (const float4*)(logits + img * HW);

    // load 10 target rows: r0-1 .. r0+8
    float4 T[10];
#pragma unroll
    for (int j = 0; j < 10; ++j) {
        const int row = r0 - 1 + j;
        T[j] = (row >= 0 && row < HH) ? tg4[row * 128 + c4]
                                      : make_float4(0.f, 0.f, 0.f, 0.f);
    }

    // publish boundary column triple-sums for the other half-wave
    if (half == 0 && lane == 63) {
#pragma unroll
        for (int j = 0; j < 8; ++j) s_bL[strip][j] = T[j].w + T[j + 1].w + T[j + 2].w;
    }
    if (half == 1 && lane == 0) {
#pragma unroll
        for (int j = 0; j < 8; ++j) s_bR[strip][j] = T[j].x + T[j + 1].x + T[j + 2].x;
    }
    __syncthreads();

    float bce_s = 0.f, bceE_s = 0.f, sy_s = 0.f, spy_s = 0.f, P_s = 0.f;

#pragma unroll
    for (int j = 0; j < 8; ++j) {
        const float4 X = lg4[(r0 + j) * 128 + c4];

        const float cs0 = T[j].x + T[j + 1].x + T[j + 2].x;
        const float cs1 = T[j].y + T[j + 1].y + T[j + 2].y;
        const float cs2 = T[j].z + T[j + 1].z + T[j + 2].z;
        const float cs3 = T[j].w + T[j + 1].w + T[j + 2].w;

        const float upL = __shfl_up(cs3, 1);
        const float dnR = __shfl_down(cs0, 1);
        const float csL = (lane == 0)  ? (half ? s_bL[strip][j] : 0.f) : upL;
        const float csR = (lane == 63) ? (half ? 0.f : s_bR[strip][j]) : dnR;

        const float w0 = csL + cs0 + cs1;
        const float w1 = cs0 + cs1 + cs2;
        const float w2 = cs1 + cs2 + cs3;
        const float w3 = cs2 + cs3 + csR;

        process_elem(X.x, T[j + 1].x, w0, bce_s, bceE_s, sy_s, spy_s, P_s, s_cnt);
        process_elem(X.y, T[j + 1].y, w1, bce_s, bceE_s, sy_s, spy_s, P_s, s_cnt);
        process_elem(X.z, T[j + 1].z, w2, bce_s, bceE_s, sy_s, spy_s, P_s, s_cnt);
        process_elem(X.w, T[j + 1].w, w3, bce_s, bceE_s, sy_s, spy_s, P_s, s_cnt);
    }
    __syncthreads();

    // flush histogram to global (packed counts)
    unsigned* g_c = ws->cnt + img * K_BINS;
    for (int i = tid; i < K_BINS; i += 256) {
        const unsigned cpk = s_cnt[i];
        if (cpk) atomicAdd(&g_c[i], cpk);
    }

    // block reduction of 5 accumulators
    for (int off = 32; off; off >>= 1) {
        bce_s  += __shfl_down(bce_s, off);
        bceE_s += __shfl_down(bceE_s, off);
        sy_s   += __shfl_down(sy_s, off);
        spy_s  += __shfl_down(spy_s, off);
        P_s    += __shfl_down(P_s, off);
    }
    if (lane == 0) {
        red[wave][0] = bce_s; red[wave][1] = bceE_s; red[wave][2] = sy_s;
        red[wave][3] = spy_s; red[wave][4] = P_s;
    }
    __syncthreads();
    if (tid == 0) {
        float a = 0.f, b = 0.f, c2 = 0.f, d = 0.f, e2 = 0.f;
        for (int w = 0; w < 4; ++w) {
            a += red[w][0]; b += red[w][1]; c2 += red[w][2];
            d += red[w][3]; e2 += red[w][4];
        }
        atomicAdd(&ws->bce_sum, a);
        atomicAdd(&ws->bceE_sum, b);
        atomicAdd(&ws->sy[img], c2);
        atomicAdd(&ws->spy[img], d);
        atomicAdd(&ws->Pim[img], e2);
    }
}

__global__ __launch_bounds__(256) void kernelB(Ws* __restrict__ ws) {
    __shared__ unsigned sc_a[256];
    __shared__ unsigned sc_p[256];
    __shared__ double   dred[4];

    const int img = blockIdx.x;
    const int tid = threadIdx.x;
    const unsigned* __restrict__ cn = ws->cnt + img * K_BINS;

    // each thread handles 4 bins in descending-bin order
    unsigned la[4], lp[4];
    float    me[4];
    unsigned tot_a = 0, tot_p = 0;
#pragma unroll
    for (int j = 0; j < 4; ++j) {
        const int k = K_BINS - 1 - (tid * 4 + j);
        const unsigned cpk = cn[k];
        la[j] = cpk & 0xFFFFu; lp[j] = cpk >> 16;
        me[j] = ((float)k + 0.5f) * BIN_W;          // bin-midpoint error value
        tot_a += la[j]; tot_p += lp[j];
    }

    // block-wide inclusive scan of per-thread totals
    sc_a[tid] = tot_a; sc_p[tid] = tot_p;
    __syncthreads();
    for (int off = 1; off < 256; off <<= 1) {
        unsigned va = (tid >= off) ? sc_a[tid - off] : 0u;
        unsigned vp = (tid >= off) ? sc_p[tid - off] : 0u;
        __syncthreads();
        sc_a[tid] += va; sc_p[tid] += vp;
        __syncthreads();
    }
    const unsigned excl_a = sc_a[tid] - tot_a;
    const unsigned excl_p = sc_p[tid] - tot_p;

    const double P = (double)ws->Pim[img];
    double run_a = (double)excl_a, run_p = (double)excl_p;
    double contrib = 0.0;
#pragma unroll
    for (int j = 0; j < 4; ++j) {
        const double m = (double)la[j];
        const double p = (double)lp[j];
        if (la[j]) {
            const double u = P + (run_a + 0.5 * m) - (run_p + 0.5 * p);
            const double c = run_p + 0.5 * p;
            contrib += (double)(lp[j] * me[j]) / u;                  // positives: dJ = 1/u
            const double den = u * (u - 1.0);
            if (den > 0.0)
                contrib += (double)((la[j] - lp[j]) * me[j]) * (P - c) / den;  // negatives
        }
        run_a += m; run_p += p;
    }

    for (int off = 32; off; off >>= 1) contrib += __shfl_down(contrib, off);
    const int wave = tid >> 6;
    const int lane = tid & 63;
    if (lane == 0) dred[wave] = contrib;
    __syncthreads();
    if (tid == 0) {
        double tot = dred[0] + dred[1] + dred[2] + dred[3];
        atomicAdd(&ws->lov_sum, (float)tot);
    }
}

__global__ __launch_bounds__(64) void kernelC(const Ws* __restrict__ ws,
                                              float* __restrict__ out) {
    const int lane = threadIdx.x;
    float dsum = 0.f;
    if (lane < NB) {
        const float num = 2.f * ws->sy[lane];
        const float den = ws->spy[lane] + 1e-7f;
        dsum = num / den;
    }
    for (int off = 32; off; off >>= 1) dsum += __shfl_down(dsum, off);
    if (lane == 0) {
        const float invN = 1.f / (float)NTOT;
        const float bce      = ws->bce_sum * invN;
        const float boundary = (ws->bce_sum + 2.f * ws->bceE_sum) * invN;
        const float dice     = 1.f - dsum / (float)NB;
        const float lov      = ws->lov_sum / (float)NB;
        out[0] = 0.3f * bce + 0.3f * dice + 0.2f * boundary + 0.2f * lov;
    }
}

extern "C" void kernel_launch(void* const* d_in, const int* in_sizes, int n_in,
                              void* d_out, int out_size, void* d_ws, size_t ws_size,
                              hipStream_t stream) {
    const float* logits  = (const float*)d_in[0];
    const float* targets = (const float*)d_in[1];
    float* out = (float*)d_out;
    Ws* ws = (Ws*)d_ws;

    (void)hipMemsetAsync(d_ws, 0, sizeof(Ws), stream);
    kernelA<<<NB * BPI, 256, 0, stream>>>(logits, targets, ws);
    kernelB<<<NB, 256, 0, stream>>>(ws);
    kernelC<<<1, 64, 0, stream>>>(ws, out);
}